// Round 5
// baseline (101.926 us; speedup 1.0000x reference)
//
#include <hip/hip_runtime.h>
#include <hip/hip_bf16.h>

// ---------------------------------------------------------------------------
// Fused causal attention head: B=4, T=4096, E=128, D=64, fp32 in/out.
// prep_w (W -> WT bf16) -> proj (x@W MFMA; q,k row-major bf16; V transposed
// to vt[d][t]) -> attn_partial (split-KV flash, SWAPPED-QK^T in-register
// softmax, zero LDS, P^T->B-frag via bpermute exchange, bf16 partials)
// -> attn_combine. Tiered by ws_size: NCH=16 / NCH=8 / direct.
// ---------------------------------------------------------------------------

typedef __attribute__((ext_vector_type(4))) float  f32x4;
typedef __attribute__((ext_vector_type(4))) unsigned int u32x4;
typedef __attribute__((ext_vector_type(8))) __bf16 bf16x8;
typedef __attribute__((ext_vector_type(8))) unsigned short u16x8;
typedef __attribute__((ext_vector_type(4))) unsigned short u16x4;

#define T_SEQ 4096
#define DH    64
#define EDIM  128
#define KVB   64

__device__ __forceinline__ unsigned short f2bf(float f) {
    unsigned int x = __builtin_bit_cast(unsigned int, f);
    unsigned int r = x + 0x7fffu + ((x >> 16) & 1u);   // RNE
    return (unsigned short)(r >> 16);
}

__device__ __forceinline__ unsigned int cvt_pk_bf16(float lo, float hi) {
    unsigned int d;
    asm("v_cvt_pk_bf16_f32 %0, %1, %2" : "=v"(d) : "v"(lo), "v"(hi));
    return d;
}

__device__ __forceinline__ f32x4 mfma_bf16(u16x8 a, u16x8 b, f32x4 c) {
    return __builtin_amdgcn_mfma_f32_16x16x32_bf16(
        __builtin_bit_cast(bf16x8, a), __builtin_bit_cast(bf16x8, b), c, 0, 0, 0);
}

// --------------------------- prep_w -----------------------------------------
__global__ __launch_bounds__(256) void prep_w_kernel(
    const float* __restrict__ wq, const float* __restrict__ wk,
    const float* __restrict__ wv, unsigned short* __restrict__ wt)
{
    int o = blockIdx.x * 256 + threadIdx.x;
    int m   = o >> 13;
    int rem = o & 8191;
    int d = rem >> 7, e = rem & 127;
    const float* W = (m == 0) ? wq : (m == 1) ? wk : wv;
    wt[o] = f2bf(W[e * DH + d]);
}

// --------------------------- proj: q,k row-major; v transposed --------------
__global__ __launch_bounds__(64) void proj_kernel(
    const float* __restrict__ x, const unsigned short* __restrict__ wt,
    unsigned short* __restrict__ qw, unsigned short* __restrict__ kw,
    unsigned short* __restrict__ vt)
{
    const int l   = threadIdx.x;
    const int l15 = l & 15;
    const int lg  = l >> 4;
    const int row0 = blockIdx.x * 16;      // global row (b*4096 + t)
    const int b    = row0 >> 12;
    const int t0   = row0 & 4095;

    u16x8 af[4];
    #pragma unroll
    for (int kt = 0; kt < 4; ++kt) {
        const float* xp = x + (row0 + l15) * EDIM + kt * 32 + lg * 8;
        f32x4 a = *(const f32x4*)xp;
        f32x4 bb = *(const f32x4*)(xp + 4);
        af[kt] = u16x8{ f2bf(a[0]), f2bf(a[1]), f2bf(a[2]), f2bf(a[3]),
                        f2bf(bb[0]), f2bf(bb[1]), f2bf(bb[2]), f2bf(bb[3]) };
    }

    unsigned short* outs[2] = { qw, kw };
    #pragma unroll
    for (int m = 0; m < 2; ++m) {
        #pragma unroll
        for (int nt = 0; nt < 4; ++nt) {
            f32x4 acc = {};
            #pragma unroll
            for (int kt = 0; kt < 4; ++kt) {
                u16x8 bfrag = *(const u16x8*)(wt + (m * 64 + nt * 16 + l15) * EDIM
                                                 + kt * 32 + lg * 8);
                acc = mfma_bf16(af[kt], bfrag, acc);
            }
            const float sc = (m == 0) ? 0.125f : 1.0f;  // fold 1/sqrt(64) into q
            #pragma unroll
            for (int r = 0; r < 4; ++r)
                outs[m][(row0 + lg * 4 + r) * DH + nt * 16 + l15] = f2bf(acc[r] * sc);
        }
    }

    // v: store transposed vt[b][d][t]
    #pragma unroll
    for (int nt = 0; nt < 4; ++nt) {
        f32x4 acc = {};
        #pragma unroll
        for (int kt = 0; kt < 4; ++kt) {
            u16x8 bfrag = *(const u16x8*)(wt + (2 * 64 + nt * 16 + l15) * EDIM
                                             + kt * 32 + lg * 8);
            acc = mfma_bf16(af[kt], bfrag, acc);
        }
        u16x4 pv = { f2bf(acc[0]), f2bf(acc[1]), f2bf(acc[2]), f2bf(acc[3]) };
        *(u16x4*)(vt + ((size_t)(b * DH + nt * 16 + l15)) * T_SEQ + t0 + lg * 4) = pv;
    }
}

// --------------------------- swapped-QK^T flash core ------------------------
// Lane (l15, lg): S^T scores for q = rt*16+l15 at keys kv0+nt*16+lg*4+r.
// O^T accumulator: o[rt][dt][r] = O[q=rt*16+l15][d=dt*16+lg*4+r].
struct St32s {
    f32x4 o[2][4];
    float m[2], l[2];
};

__device__ __forceinline__ void flash32s(
    const unsigned short* __restrict__ kp,   // K for batch, [t][d]
    const unsigned short* __restrict__ vp,   // V^T for batch, [d][t]
    int qrow0, int kv_begin, int kv_end,
    const u16x8 qf[2][2], St32s& st, int l15, int lg)
{
    const int src0 = l15 + 32 * (lg & 1);    // exchange source lanes
    const int src1 = src0 + 16;
    const bool hi  = (lg >> 1) != 0;         // plane select

    for (int kv0 = kv_begin; kv0 < kv_end; kv0 += KVB) {
        // ---- K A-fragments (row = key = l15-part, k = d) ----
        u16x8 kf[4][2];
        #pragma unroll
        for (int nt = 0; nt < 4; ++nt)
            #pragma unroll
            for (int kt = 0; kt < 2; ++kt)
                kf[nt][kt] = *(const u16x8*)(kp + (kv0 + nt * 16 + l15) * DH
                                                + kt * 32 + lg * 8);

        // ---- S^T = K Q^T ----
        f32x4 s[2][4];
        __builtin_amdgcn_s_setprio(1);
        #pragma unroll
        for (int rt = 0; rt < 2; ++rt)
            #pragma unroll
            for (int nt = 0; nt < 4; ++nt) {
                f32x4 a = {};
                a = mfma_bf16(kf[nt][0], qf[rt][0], a);
                a = mfma_bf16(kf[nt][1], qf[rt][1], a);
                s[rt][nt] = a;
            }
        __builtin_amdgcn_s_setprio(0);

        // ---- causal mask (diagonal-straddling tiles only) ----
        if (kv0 + KVB - 1 > qrow0) {
            #pragma unroll
            for (int rt = 0; rt < 2; ++rt)
                #pragma unroll
                for (int nt = 0; nt < 4; ++nt)
                    #pragma unroll
                    for (int r = 0; r < 4; ++r) {
                        int kj = kv0 + nt * 16 + lg * 4 + r;
                        int qi = qrow0 + rt * 16 + l15;
                        if (kj > qi) s[rt][nt][r] = -1e30f;
                    }
        }

        // ---- in-register online softmax (2 shfls per reduce) ----
        float sc2[2];
        bool grow = false;
        unsigned int pk[2][4][2];
        #pragma unroll
        for (int rt = 0; rt < 2; ++rt) {
            float mx = s[rt][0][0];
            #pragma unroll
            for (int nt = 0; nt < 4; ++nt)
                #pragma unroll
                for (int r = 0; r < 4; ++r)
                    mx = fmaxf(mx, s[rt][nt][r]);
            mx = fmaxf(mx, __shfl_xor(mx, 16));
            mx = fmaxf(mx, __shfl_xor(mx, 32));

            float mold = st.m[rt];
            float mnew = fmaxf(mold, mx);
            grow |= (mx > mold);
            float sc = __expf(mold - mnew);
            sc2[rt] = sc;
            st.m[rt] = mnew;

            float rs = 0.0f;
            #pragma unroll
            for (int nt = 0; nt < 4; ++nt)
                #pragma unroll
                for (int r = 0; r < 4; ++r) {
                    float p = __expf(s[rt][nt][r] - mnew);
                    s[rt][nt][r] = p;
                    rs += p;
                }
            rs += __shfl_xor(rs, 16);
            rs += __shfl_xor(rs, 32);
            st.l[rt] = st.l[rt] * sc + rs;

            // pack P^T to bf16 pairs (keys r=(0,1),(2,3) per nt)
            #pragma unroll
            for (int nt = 0; nt < 4; ++nt) {
                pk[rt][nt][0] = cvt_pk_bf16(s[rt][nt][0], s[rt][nt][1]);
                pk[rt][nt][1] = cvt_pk_bf16(s[rt][nt][2], s[rt][nt][3]);
            }
        }
        if (__any(grow)) {
            #pragma unroll
            for (int rt = 0; rt < 2; ++rt)
                #pragma unroll
                for (int dt = 0; dt < 4; ++dt)
                    st.o[rt][dt] *= sc2[rt];
        }

        // ---- O^T += V^T P^T  (B-frag built via 4-lane bpermute exchange) ----
        __builtin_amdgcn_s_setprio(1);
        #pragma unroll
        for (int kt = 0; kt < 2; ++kt) {
            u16x8 vf[4];
            #pragma unroll
            for (int dt = 0; dt < 4; ++dt)
                vf[dt] = *(const u16x8*)(vp + (size_t)(dt * 16 + l15) * T_SEQ
                                            + kv0 + kt * 32 + lg * 8);
            #pragma unroll
            for (int rt = 0; rt < 2; ++rt) {
                unsigned int pb[4];
                #pragma unroll
                for (int t = 0; t < 4; ++t) {
                    int src = (t < 2) ? src0 : src1;
                    unsigned int pa = __shfl(pk[rt][2 * kt][t & 1], src);
                    unsigned int pbv = __shfl(pk[rt][2 * kt + 1][t & 1], src);
                    pb[t] = hi ? pbv : pa;
                }
                u32x4 pbq = { pb[0], pb[1], pb[2], pb[3] };
                u16x8 pbf = __builtin_bit_cast(u16x8, pbq);
                #pragma unroll
                for (int dt = 0; dt < 4; ++dt)
                    st.o[rt][dt] = mfma_bf16(vf[dt], pbf, st.o[rt][dt]);
            }
        }
        __builtin_amdgcn_s_setprio(0);
    }
}

__device__ __forceinline__ void load_qf(
    const unsigned short* __restrict__ qg, int base, int qrow0,
    int l15, int lg, u16x8 qf[2][2])
{
    #pragma unroll
    for (int rt = 0; rt < 2; ++rt) {
        const unsigned short* qrow = qg + (base + qrow0 + rt * 16 + l15) * DH;
        qf[rt][0] = *(const u16x8*)(qrow + 0 + lg * 8);
        qf[rt][1] = *(const u16x8*)(qrow + 32 + lg * 8);
    }
}

// --------------------------- phase 1: split-KV partials ---------------------
template<int L2N>
__global__ __launch_bounds__(64, 4) void attn_partial_kernel(
    const unsigned short* __restrict__ qg, const unsigned short* __restrict__ kg,
    const unsigned short* __restrict__ vt,
    unsigned short* __restrict__ po, float* __restrict__ pm, float* __restrict__ pl)
{
    constexpr int NCHT = 1 << L2N;
    constexpr int CH_KEYS = T_SEQ / NCHT;
    const int bid = blockIdx.x;           // ((b*128 + q32) << L2N) + ch
    const int ch  = bid & (NCHT - 1);
    const int q32 = (bid >> L2N) & 127;
    const int b   = bid >> (7 + L2N);
    const int qrow0 = q32 * 32;
    if (ch * CH_KEYS > qrow0) return;     // beyond causal range

    const int l = threadIdx.x, l15 = l & 15, lg = l >> 4;
    const int base = b * T_SEQ;
    const int kvb  = ch * CH_KEYS;
    const int kve  = min(kvb + CH_KEYS, qrow0 + 32);

    u16x8 qf[2][2];
    load_qf(qg, base, qrow0, l15, lg, qf);

    St32s st;
    #pragma unroll
    for (int rt = 0; rt < 2; ++rt) {
        #pragma unroll
        for (int dt = 0; dt < 4; ++dt) st.o[rt][dt] = f32x4{};
        st.m[rt] = -1e30f; st.l[rt] = 0.0f;
    }

    flash32s(kg + (size_t)base * DH, vt + (size_t)b * DH * T_SEQ,
             qrow0, kvb, kve, qf, st, l15, lg);

    const int pidx = ((b * 128 + q32) << L2N) + ch;
    unsigned short* pob = po + (size_t)pidx * 2048;
    #pragma unroll
    for (int rt = 0; rt < 2; ++rt) {
        int row = rt * 16 + l15;
        #pragma unroll
        for (int dt = 0; dt < 4; ++dt) {
            unsigned int w0 = cvt_pk_bf16(st.o[rt][dt][0], st.o[rt][dt][1]);
            unsigned int w1 = cvt_pk_bf16(st.o[rt][dt][2], st.o[rt][dt][3]);
            *(unsigned int*)&pob[row * 64 + dt * 16 + lg * 4]     = w0;
            *(unsigned int*)&pob[row * 64 + dt * 16 + lg * 4 + 2] = w1;
        }
        if (lg == 0) {
            pm[pidx * 32 + row] = st.m[rt];
            pl[pidx * 32 + row] = st.l[rt];
        }
    }
}

// --------------------------- phase 2: combine -------------------------------
template<int L2N>
__global__ __launch_bounds__(256) void attn_combine_kernel(
    const unsigned short* __restrict__ po, const float* __restrict__ pm,
    const float* __restrict__ pl, float* __restrict__ out)
{
    constexpr int NCHT = 1 << L2N;
    const int tb  = blockIdx.x;           // b*128 + q32
    const int q32 = tb & 127;
    const int nch = (q32 >> (7 - L2N)) + 1;
    const int q   = threadIdx.x >> 3;     // 0..31
    const int d0  = (threadIdx.x & 7) * 8;
    const int bp  = tb << L2N;

    float mstar = -1e30f;
    float m_i[NCHT];
    #pragma unroll
    for (int i = 0; i < NCHT; ++i)
        if (i < nch) {
            m_i[i] = pm[(bp + i) * 32 + q];
            mstar = fmaxf(mstar, m_i[i]);
        }
    float w_i[NCHT];
    float lsum = 0.0f;
    #pragma unroll
    for (int i = 0; i < NCHT; ++i)
        if (i < nch) {
            w_i[i] = __expf(m_i[i] - mstar);
            lsum += w_i[i] * pl[(bp + i) * 32 + q];
        }
    const float inv = 1.0f / lsum;

    float acc[8] = {};
    #pragma unroll
    for (int i = 0; i < NCHT; ++i)
        if (i < nch) {
            u16x8 v = *(const u16x8*)&po[(size_t)(bp + i) * 2048 + q * 64 + d0];
            #pragma unroll
            for (int j = 0; j < 8; ++j) {
                unsigned int u = (unsigned int)v[j] << 16;
                acc[j] += w_i[i] * __builtin_bit_cast(float, u);
            }
        }
    float* op = out + (size_t)(tb * 32 + q) * DH + d0;
    f32x4 o0 = { acc[0] * inv, acc[1] * inv, acc[2] * inv, acc[3] * inv };
    f32x4 o1 = { acc[4] * inv, acc[5] * inv, acc[6] * inv, acc[7] * inv };
    *(f32x4*)op = o0;
    *(f32x4*)(op + 4) = o1;
}

// --------------------------- fallback: direct (no partials) -----------------
__global__ __launch_bounds__(64, 4) void attn_direct_kernel(
    const unsigned short* __restrict__ qg, const unsigned short* __restrict__ kg,
    const unsigned short* __restrict__ vt, float* __restrict__ out)
{
    const int bid = blockIdx.x;           // b*128 + q32
    const int q32 = bid & 127;
    const int b   = bid >> 7;
    const int l = threadIdx.x, l15 = l & 15, lg = l >> 4;
    const int qrow0 = q32 * 32;
    const int base  = b * T_SEQ;

    u16x8 qf[2][2];
    load_qf(qg, base, qrow0, l15, lg, qf);

    St32s st;
    #pragma unroll
    for (int rt = 0; rt < 2; ++rt) {
        #pragma unroll
        for (int dt = 0; dt < 4; ++dt) st.o[rt][dt] = f32x4{};
        st.m[rt] = -1e30f; st.l[rt] = 0.0f;
    }

    flash32s(kg + (size_t)base * DH, vt + (size_t)b * DH * T_SEQ,
             qrow0, 0, qrow0 + 32, qf, st, l15, lg);

    #pragma unroll
    for (int rt = 0; rt < 2; ++rt) {
        float inv = 1.0f / st.l[rt];
        int row = base + qrow0 + rt * 16 + l15;
        #pragma unroll
        for (int dt = 0; dt < 4; ++dt) {
            f32x4 ov = st.o[rt][dt] * inv;
            *(f32x4*)&out[(size_t)row * DH + dt * 16 + lg * 4] = ov;
        }
    }
}

// ---------------------------------------------------------------------------
extern "C" void kernel_launch(void* const* d_in, const int* in_sizes, int n_in,
                              void* d_out, int out_size, void* d_ws, size_t ws_size,
                              hipStream_t stream)
{
    const float* x  = (const float*)d_in[0];
    const float* wq = (const float*)d_in[1];
    const float* wk = (const float*)d_in[2];
    const float* wv = (const float*)d_in[3];
    float* out = (float*)d_out;

    // ws layout:
    //   wt  bf16 [3][64][128]   @ 0        (reserve 64 KB)
    //   qw  bf16 [16384][64]    @ 65536    (2 MB)
    //   kw  bf16 [16384][64]    @ +2 MB
    //   vt  bf16 [4][64][4096]  @ +4 MB
    //   po  bf16 [slots][32][64]  pm/pl f32 [slots][32]
    unsigned short* wt = (unsigned short*)d_ws;
    unsigned short* qw = (unsigned short*)((char*)d_ws + 65536);
    unsigned short* kw = qw + (size_t)16384 * DH;
    unsigned short* vt = kw + (size_t)16384 * DH;
    const size_t po_off = 65536u + 3u * 16384u * DH * 2u;   // 6.36 MB

    prep_w_kernel<<<96, 256, 0, stream>>>(wq, wk, wv, wt);
    proj_kernel<<<1024, 64, 0, stream>>>(x, wt, qw, kw, vt);

    // tier 1: NCH=16 (chunks of 256 keys)
    {
        const size_t slots = 4u * 128u * 16u;               // 8192
        const size_t po_sz = slots * 2048 * 2;              // 33.5 MB
        const size_t pm_off = po_off + po_sz;
        const size_t pl_off = pm_off + slots * 32 * 4;
        const size_t need   = pl_off + slots * 32 * 4;
        if (ws_size >= need) {
            unsigned short* po = (unsigned short*)((char*)d_ws + po_off);
            float* pm = (float*)((char*)d_ws + pm_off);
            float* pl = (float*)((char*)d_ws + pl_off);
            attn_partial_kernel<4><<<4 * 128 * 16, 64, 0, stream>>>(qw, kw, vt, po, pm, pl);
            attn_combine_kernel<4><<<512, 256, 0, stream>>>(po, pm, pl, out);
            return;
        }
    }
    // tier 2: NCH=8 (chunks of 512 keys)
    {
        const size_t slots = 4u * 128u * 8u;                // 4096
        const size_t po_sz = slots * 2048 * 2;              // 16.8 MB
        const size_t pm_off = po_off + po_sz;
        const size_t pl_off = pm_off + slots * 32 * 4;
        const size_t need   = pl_off + slots * 32 * 4;
        if (ws_size >= need) {
            unsigned short* po = (unsigned short*)((char*)d_ws + po_off);
            float* pm = (float*)((char*)d_ws + pm_off);
            float* pl = (float*)((char*)d_ws + pl_off);
            attn_partial_kernel<3><<<4 * 128 * 8, 64, 0, stream>>>(qw, kw, vt, po, pm, pl);
            attn_combine_kernel<3><<<512, 256, 0, stream>>>(po, pm, pl, out);
            return;
        }
    }
    // fallback: direct
    attn_direct_kernel<<<4 * 128, 64, 0, stream>>>(qw, kw, vt, out);
}

// Round 6
// 69.899 us; speedup vs baseline: 1.4582x; 1.4582x over previous
//
#include <hip/hip_runtime.h>
#include <hip/hip_bf16.h>

// ---------------------------------------------------------------------------
// Fused causal attention head: B=4, T=4096, E=128, D=64, fp32 in/out.
// prep_w (W -> WT bf16) -> proj (x@W MFMA; q,k row-major bf16; V transposed
// to vt[d][t]) -> attn_partial (split-KV flash: 256-thr block = 128 q-rows x
// 256-key chunk; K and V^T tiles staged coalesced into LDS and shared by the
// 4 waves; swapped-QK^T in-register softmax; P^T->B-frag via bpermute)
// -> attn_combine. Fallback: direct per-wave kernel (global K/V reads).
// ---------------------------------------------------------------------------

typedef __attribute__((ext_vector_type(4))) float  f32x4;
typedef __attribute__((ext_vector_type(4))) unsigned int u32x4;
typedef __attribute__((ext_vector_type(8))) __bf16 bf16x8;
typedef __attribute__((ext_vector_type(8))) unsigned short u16x8;
typedef __attribute__((ext_vector_type(4))) unsigned short u16x4;

#define T_SEQ 4096
#define DH    64
#define EDIM  128
#define KVB   64
#define KSTR  72   // LDS row stride (u16): 16B-aligned, 2-way bank alias (free)

__device__ __forceinline__ unsigned short f2bf(float f) {
    unsigned int x = __builtin_bit_cast(unsigned int, f);
    unsigned int r = x + 0x7fffu + ((x >> 16) & 1u);   // RNE
    return (unsigned short)(r >> 16);
}

__device__ __forceinline__ unsigned int cvt_pk_bf16(float lo, float hi) {
    unsigned int d;
    asm("v_cvt_pk_bf16_f32 %0, %1, %2" : "=v"(d) : "v"(lo), "v"(hi));
    return d;
}

__device__ __forceinline__ f32x4 mfma_bf16(u16x8 a, u16x8 b, f32x4 c) {
    return __builtin_amdgcn_mfma_f32_16x16x32_bf16(
        __builtin_bit_cast(bf16x8, a), __builtin_bit_cast(bf16x8, b), c, 0, 0, 0);
}

// --------------------------- prep_w -----------------------------------------
__global__ __launch_bounds__(256) void prep_w_kernel(
    const float* __restrict__ wq, const float* __restrict__ wk,
    const float* __restrict__ wv, unsigned short* __restrict__ wt)
{
    int o = blockIdx.x * 256 + threadIdx.x;
    int m   = o >> 13;
    int rem = o & 8191;
    int d = rem >> 7, e = rem & 127;
    const float* W = (m == 0) ? wq : (m == 1) ? wk : wv;
    wt[o] = f2bf(W[e * DH + d]);
}

// --------------------------- proj: q,k row-major; v transposed --------------
__global__ __launch_bounds__(64) void proj_kernel(
    const float* __restrict__ x, const unsigned short* __restrict__ wt,
    unsigned short* __restrict__ qw, unsigned short* __restrict__ kw,
    unsigned short* __restrict__ vt)
{
    const int l   = threadIdx.x;
    const int l15 = l & 15;
    const int lg  = l >> 4;
    const int row0 = blockIdx.x * 16;      // global row (b*4096 + t)
    const int b    = row0 >> 12;
    const int t0   = row0 & 4095;

    u16x8 af[4];
    #pragma unroll
    for (int kt = 0; kt < 4; ++kt) {
        const float* xp = x + (row0 + l15) * EDIM + kt * 32 + lg * 8;
        f32x4 a = *(const f32x4*)xp;
        f32x4 bb = *(const f32x4*)(xp + 4);
        af[kt] = u16x8{ f2bf(a[0]), f2bf(a[1]), f2bf(a[2]), f2bf(a[3]),
                        f2bf(bb[0]), f2bf(bb[1]), f2bf(bb[2]), f2bf(bb[3]) };
    }

    unsigned short* outs[2] = { qw, kw };
    #pragma unroll
    for (int m = 0; m < 2; ++m) {
        #pragma unroll
        for (int nt = 0; nt < 4; ++nt) {
            f32x4 acc = {};
            #pragma unroll
            for (int kt = 0; kt < 4; ++kt) {
                u16x8 bfrag = *(const u16x8*)(wt + (m * 64 + nt * 16 + l15) * EDIM
                                                 + kt * 32 + lg * 8);
                acc = mfma_bf16(af[kt], bfrag, acc);
            }
            const float sc = (m == 0) ? 0.125f : 1.0f;  // fold 1/sqrt(64) into q
            #pragma unroll
            for (int r = 0; r < 4; ++r)
                outs[m][(row0 + lg * 4 + r) * DH + nt * 16 + l15] = f2bf(acc[r] * sc);
        }
    }

    // v: store transposed vt[b][d][t]
    #pragma unroll
    for (int nt = 0; nt < 4; ++nt) {
        f32x4 acc = {};
        #pragma unroll
        for (int kt = 0; kt < 4; ++kt) {
            u16x8 bfrag = *(const u16x8*)(wt + (2 * 64 + nt * 16 + l15) * EDIM
                                             + kt * 32 + lg * 8);
            acc = mfma_bf16(af[kt], bfrag, acc);
        }
        u16x4 pv = { f2bf(acc[0]), f2bf(acc[1]), f2bf(acc[2]), f2bf(acc[3]) };
        *(u16x4*)(vt + ((size_t)(b * DH + nt * 16 + l15)) * T_SEQ + t0 + lg * 4) = pv;
    }
}

// --------------------------- per-wave flash state ---------------------------
// Lane (l15, lg): S^T scores for q = rt*16+l15 at keys kv0+nt*16+lg*4+r.
// O^T accumulator: o[rt][dt][r] = O[q=rt*16+l15][d=dt*16+lg*4+r].
struct St32s {
    f32x4 o[2][4];
    float m[2], l[2];
};

__device__ __forceinline__ void load_qf(
    const unsigned short* __restrict__ qg, int base, int qrow0,
    int l15, int lg, u16x8 qf[2][2])
{
    #pragma unroll
    for (int rt = 0; rt < 2; ++rt) {
        const unsigned short* qrow = qg + (base + qrow0 + rt * 16 + l15) * DH;
        qf[rt][0] = *(const u16x8*)(qrow + 0 + lg * 8);
        qf[rt][1] = *(const u16x8*)(qrow + 32 + lg * 8);
    }
}

// --------------------------- phase 1: LDS-staged split-KV flash -------------
__global__ __launch_bounds__(256, 4) void attn_partial_kernel(
    const unsigned short* __restrict__ qg, const unsigned short* __restrict__ kg,
    const unsigned short* __restrict__ vt,
    unsigned short* __restrict__ po, float* __restrict__ pm, float* __restrict__ pl)
{
    const int bid  = blockIdx.x;          // (b*32 + q128)*16 + ch
    const int ch   = bid & 15;
    const int q128 = (bid >> 4) & 31;
    const int b    = bid >> 9;
    if (2 * ch > q128) return;            // chunk beyond causal range

    __shared__ unsigned short K_lds[64 * KSTR];
    __shared__ unsigned short V_lds[64 * KSTR];

    const int tid = threadIdx.x;
    const int w   = tid >> 6;
    const int l   = tid & 63;
    const int l15 = l & 15;
    const int lg  = l >> 4;

    const int base   = b * T_SEQ;
    const int qrow0w = q128 * 128 + w * 32;     // wave's 32 q-rows
    const int kvb = ch * 256;
    const int kve = min(kvb + 256, q128 * 128 + 128);

    u16x8 qf[2][2];
    load_qf(qg, base, qrow0w, l15, lg, qf);

    St32s st;
    #pragma unroll
    for (int rt = 0; rt < 2; ++rt) {
        #pragma unroll
        for (int dt = 0; dt < 4; ++dt) st.o[rt][dt] = f32x4{};
        st.m[rt] = -1e30f; st.l[rt] = 0.0f;
    }

    const int src0 = l15 + 32 * (lg & 1);       // P exchange source lanes
    const int src1 = src0 + 16;
    const bool hi  = (lg >> 1) != 0;

    for (int kv0 = kvb; kv0 < kve; kv0 += KVB) {
        // ---- stage K[kv0..+64][d] and V^T[d][kv0..+64], coalesced ----
        #pragma unroll
        for (int i = 0; i < 2; ++i) {
            int idx = tid + i * 256;            // 0..511
            int row = idx >> 3;                 // 8 x 16B per 128B row
            int c8  = (idx & 7) * 8;
            *(u16x8*)&K_lds[row * KSTR + c8] =
                *(const u16x8*)(kg + (size_t)(base + kv0 + row) * DH + c8);
            *(u16x8*)&V_lds[row * KSTR + c8] =
                *(const u16x8*)(vt + (size_t)(b * DH + row) * T_SEQ + kv0 + c8);
        }
        __syncthreads();

        if (kv0 <= qrow0w + 31) {               // wave-uniform causal skip
            // ---- K A-fragments from LDS ----
            u16x8 kf[4][2];
            #pragma unroll
            for (int nt = 0; nt < 4; ++nt)
                #pragma unroll
                for (int kt = 0; kt < 2; ++kt)
                    kf[nt][kt] = *(const u16x8*)&K_lds[(nt * 16 + l15) * KSTR
                                                       + kt * 32 + lg * 8];

            // ---- S^T = K Q^T ----
            f32x4 s[2][4];
            __builtin_amdgcn_s_setprio(1);
            #pragma unroll
            for (int rt = 0; rt < 2; ++rt)
                #pragma unroll
                for (int nt = 0; nt < 4; ++nt) {
                    f32x4 a = {};
                    a = mfma_bf16(kf[nt][0], qf[rt][0], a);
                    a = mfma_bf16(kf[nt][1], qf[rt][1], a);
                    s[rt][nt] = a;
                }
            __builtin_amdgcn_s_setprio(0);

            // ---- causal mask (diagonal-straddling tiles only) ----
            if (kv0 + KVB - 1 > qrow0w) {
                #pragma unroll
                for (int rt = 0; rt < 2; ++rt)
                    #pragma unroll
                    for (int nt = 0; nt < 4; ++nt)
                        #pragma unroll
                        for (int r = 0; r < 4; ++r) {
                            int kj = kv0 + nt * 16 + lg * 4 + r;
                            int qi = qrow0w + rt * 16 + l15;
                            if (kj > qi) s[rt][nt][r] = -1e30f;
                        }
            }

            // ---- in-register online softmax (2 shfls per reduce) ----
            float sc2[2];
            bool grow = false;
            unsigned int pk[2][4][2];
            #pragma unroll
            for (int rt = 0; rt < 2; ++rt) {
                float mx = s[rt][0][0];
                #pragma unroll
                for (int nt = 0; nt < 4; ++nt)
                    #pragma unroll
                    for (int r = 0; r < 4; ++r)
                        mx = fmaxf(mx, s[rt][nt][r]);
                mx = fmaxf(mx, __shfl_xor(mx, 16));
                mx = fmaxf(mx, __shfl_xor(mx, 32));

                float mold = st.m[rt];
                float mnew = fmaxf(mold, mx);
                grow |= (mx > mold);
                float sc = __expf(mold - mnew);
                sc2[rt] = sc;
                st.m[rt] = mnew;

                float rs = 0.0f;
                #pragma unroll
                for (int nt = 0; nt < 4; ++nt)
                    #pragma unroll
                    for (int r = 0; r < 4; ++r) {
                        float p = __expf(s[rt][nt][r] - mnew);
                        s[rt][nt][r] = p;
                        rs += p;
                    }
                rs += __shfl_xor(rs, 16);
                rs += __shfl_xor(rs, 32);
                st.l[rt] = st.l[rt] * sc + rs;

                #pragma unroll
                for (int nt = 0; nt < 4; ++nt) {
                    pk[rt][nt][0] = cvt_pk_bf16(s[rt][nt][0], s[rt][nt][1]);
                    pk[rt][nt][1] = cvt_pk_bf16(s[rt][nt][2], s[rt][nt][3]);
                }
            }
            if (__any(grow)) {
                #pragma unroll
                for (int rt = 0; rt < 2; ++rt)
                    #pragma unroll
                    for (int dt = 0; dt < 4; ++dt)
                        st.o[rt][dt] *= sc2[rt];
            }

            // ---- O^T += V^T P^T (V^T A-frags from LDS; P via bpermute) ----
            __builtin_amdgcn_s_setprio(1);
            #pragma unroll
            for (int kt = 0; kt < 2; ++kt) {
                u16x8 vf[4];
                #pragma unroll
                for (int dt = 0; dt < 4; ++dt)
                    vf[dt] = *(const u16x8*)&V_lds[(dt * 16 + l15) * KSTR
                                                   + kt * 32 + lg * 8];
                #pragma unroll
                for (int rt = 0; rt < 2; ++rt) {
                    unsigned int pb[4];
                    #pragma unroll
                    for (int t = 0; t < 4; ++t) {
                        int src = (t < 2) ? src0 : src1;
                        unsigned int pa  = __shfl(pk[rt][2 * kt][t & 1], src);
                        unsigned int pbv = __shfl(pk[rt][2 * kt + 1][t & 1], src);
                        pb[t] = hi ? pbv : pa;
                    }
                    u32x4 pbq = { pb[0], pb[1], pb[2], pb[3] };
                    u16x8 pbf = __builtin_bit_cast(u16x8, pbq);
                    #pragma unroll
                    for (int dt = 0; dt < 4; ++dt)
                        st.o[rt][dt] = mfma_bf16(vf[dt], pbf, st.o[rt][dt]);
                }
            }
            __builtin_amdgcn_s_setprio(0);
        }
        __syncthreads();
    }

    // ---- write partials (bf16 O, f32 m/l) ----
    const int pidx = (b * 32 + q128) * 16 + ch;
    unsigned short* pob = po + (size_t)pidx * 8192;   // [128][64] bf16
    #pragma unroll
    for (int rt = 0; rt < 2; ++rt) {
        int row = w * 32 + rt * 16 + l15;
        #pragma unroll
        for (int dt = 0; dt < 4; ++dt) {
            unsigned int w0 = cvt_pk_bf16(st.o[rt][dt][0], st.o[rt][dt][1]);
            unsigned int w1 = cvt_pk_bf16(st.o[rt][dt][2], st.o[rt][dt][3]);
            *(unsigned int*)&pob[row * 64 + dt * 16 + lg * 4]     = w0;
            *(unsigned int*)&pob[row * 64 + dt * 16 + lg * 4 + 2] = w1;
        }
        if (lg == 0) {
            pm[pidx * 128 + row] = st.m[rt];
            pl[pidx * 128 + row] = st.l[rt];
        }
    }
}

// --------------------------- phase 2: combine -------------------------------
__global__ __launch_bounds__(256) void attn_combine_kernel(
    const unsigned short* __restrict__ po, const float* __restrict__ pm,
    const float* __restrict__ pl, float* __restrict__ out)
{
    const int blk  = blockIdx.x;          // (b*32+q128)*2 + half
    const int half = blk & 1;
    const int tb   = blk >> 1;            // b*32 + q128
    const int q128 = tb & 31;
    const int b    = tb >> 5;
    const int nch  = (q128 >> 1) + 1;
    const int row  = half * 64 + (threadIdx.x >> 2);   // 0..127
    const int d0   = (threadIdx.x & 3) * 16;
    const int bp   = tb * 16;

    float mstar = -1e30f;
    for (int i = 0; i < nch; ++i)
        mstar = fmaxf(mstar, pm[(bp + i) * 128 + row]);

    float lsum = 0.0f;
    float a[16] = {};
    for (int i = 0; i < nch; ++i) {
        float wi = __expf(pm[(bp + i) * 128 + row] - mstar);
        lsum += wi * pl[(bp + i) * 128 + row];
        const unsigned short* p = po + (size_t)(bp + i) * 8192 + row * 64 + d0;
        u16x8 v0 = *(const u16x8*)p;
        u16x8 v1 = *(const u16x8*)(p + 8);
        #pragma unroll
        for (int j = 0; j < 8; ++j) {
            unsigned int u0 = (unsigned int)v0[j] << 16;
            unsigned int u1 = (unsigned int)v1[j] << 16;
            a[j]     += wi * __builtin_bit_cast(float, u0);
            a[8 + j] += wi * __builtin_bit_cast(float, u1);
        }
    }
    const float inv = 1.0f / lsum;
    float* op = out + (size_t)(b * T_SEQ + q128 * 128 + row) * DH + d0;
    #pragma unroll
    for (int j = 0; j < 4; ++j) {
        f32x4 o0 = { a[4*(j&1)+0 + 8*(j>>1)] * inv, a[4*(j&1)+1 + 8*(j>>1)] * inv,
                     a[4*(j&1)+2 + 8*(j>>1)] * inv, a[4*(j&1)+3 + 8*(j>>1)] * inv };
        *(f32x4*)(op + j * 4) = o0;
    }
}

// --------------------------- fallback: direct (global K/V reads) ------------
__device__ __forceinline__ void flash32s_global(
    const unsigned short* __restrict__ kp,   // K for batch, [t][d]
    const unsigned short* __restrict__ vp,   // V^T for batch, [d][t]
    int qrow0, int kv_begin, int kv_end,
    const u16x8 qf[2][2], St32s& st, int l15, int lg)
{
    const int src0 = l15 + 32 * (lg & 1);
    const int src1 = src0 + 16;
    const bool hi  = (lg >> 1) != 0;

    for (int kv0 = kv_begin; kv0 < kv_end; kv0 += KVB) {
        u16x8 kf[4][2];
        #pragma unroll
        for (int nt = 0; nt < 4; ++nt)
            #pragma unroll
            for (int kt = 0; kt < 2; ++kt)
                kf[nt][kt] = *(const u16x8*)(kp + (kv0 + nt * 16 + l15) * DH
                                                + kt * 32 + lg * 8);

        f32x4 s[2][4];
        #pragma unroll
        for (int rt = 0; rt < 2; ++rt)
            #pragma unroll
            for (int nt = 0; nt < 4; ++nt) {
                f32x4 a = {};
                a = mfma_bf16(kf[nt][0], qf[rt][0], a);
                a = mfma_bf16(kf[nt][1], qf[rt][1], a);
                s[rt][nt] = a;
            }

        if (kv0 + KVB - 1 > qrow0) {
            #pragma unroll
            for (int rt = 0; rt < 2; ++rt)
                #pragma unroll
                for (int nt = 0; nt < 4; ++nt)
                    #pragma unroll
                    for (int r = 0; r < 4; ++r) {
                        int kj = kv0 + nt * 16 + lg * 4 + r;
                        int qi = qrow0 + rt * 16 + l15;
                        if (kj > qi) s[rt][nt][r] = -1e30f;
                    }
        }

        float sc2[2];
        bool grow = false;
        unsigned int pk[2][4][2];
        #pragma unroll
        for (int rt = 0; rt < 2; ++rt) {
            float mx = s[rt][0][0];
            #pragma unroll
            for (int nt = 0; nt < 4; ++nt)
                #pragma unroll
                for (int r = 0; r < 4; ++r)
                    mx = fmaxf(mx, s[rt][nt][r]);
            mx = fmaxf(mx, __shfl_xor(mx, 16));
            mx = fmaxf(mx, __shfl_xor(mx, 32));

            float mold = st.m[rt];
            float mnew = fmaxf(mold, mx);
            grow |= (mx > mold);
            float sc = __expf(mold - mnew);
            sc2[rt] = sc;
            st.m[rt] = mnew;

            float rs = 0.0f;
            #pragma unroll
            for (int nt = 0; nt < 4; ++nt)
                #pragma unroll
                for (int r = 0; r < 4; ++r) {
                    float p = __expf(s[rt][nt][r] - mnew);
                    s[rt][nt][r] = p;
                    rs += p;
                }
            rs += __shfl_xor(rs, 16);
            rs += __shfl_xor(rs, 32);
            st.l[rt] = st.l[rt] * sc + rs;

            #pragma unroll
            for (int nt = 0; nt < 4; ++nt) {
                pk[rt][nt][0] = cvt_pk_bf16(s[rt][nt][0], s[rt][nt][1]);
                pk[rt][nt][1] = cvt_pk_bf16(s[rt][nt][2], s[rt][nt][3]);
            }
        }
        if (__any(grow)) {
            #pragma unroll
            for (int rt = 0; rt < 2; ++rt)
                #pragma unroll
                for (int dt = 0; dt < 4; ++dt)
                    st.o[rt][dt] *= sc2[rt];
        }

        #pragma unroll
        for (int kt = 0; kt < 2; ++kt) {
            u16x8 vf[4];
            #pragma unroll
            for (int dt = 0; dt < 4; ++dt)
                vf[dt] = *(const u16x8*)(vp + (size_t)(dt * 16 + l15) * T_SEQ
                                            + kv0 + kt * 32 + lg * 8);
            #pragma unroll
            for (int rt = 0; rt < 2; ++rt) {
                unsigned int pb[4];
                #pragma unroll
                for (int t = 0; t < 4; ++t) {
                    int src = (t < 2) ? src0 : src1;
                    unsigned int pa  = __shfl(pk[rt][2 * kt][t & 1], src);
                    unsigned int pbv = __shfl(pk[rt][2 * kt + 1][t & 1], src);
                    pb[t] = hi ? pbv : pa;
                }
                u32x4 pbq = { pb[0], pb[1], pb[2], pb[3] };
                u16x8 pbf = __builtin_bit_cast(u16x8, pbq);
                #pragma unroll
                for (int dt = 0; dt < 4; ++dt)
                    st.o[rt][dt] = mfma_bf16(vf[dt], pbf, st.o[rt][dt]);
            }
        }
    }
}

__global__ __launch_bounds__(64, 4) void attn_direct_kernel(
    const unsigned short* __restrict__ qg, const unsigned short* __restrict__ kg,
    const unsigned short* __restrict__ vt, float* __restrict__ out)
{
    const int bid = blockIdx.x;           // b*128 + q32
    const int q32 = bid & 127;
    const int b   = bid >> 7;
    const int l = threadIdx.x, l15 = l & 15, lg = l >> 4;
    const int qrow0 = q32 * 32;
    const int base  = b * T_SEQ;

    u16x8 qf[2][2];
    load_qf(qg, base, qrow0, l15, lg, qf);

    St32s st;
    #pragma unroll
    for (int rt = 0; rt < 2; ++rt) {
        #pragma unroll
        for (int dt = 0; dt < 4; ++dt) st.o[rt][dt] = f32x4{};
        st.m[rt] = -1e30f; st.l[rt] = 0.0f;
    }

    flash32s_global(kg + (size_t)base * DH, vt + (size_t)b * DH * T_SEQ,
                    qrow0, 0, qrow0 + 32, qf, st, l15, lg);

    #pragma unroll
    for (int rt = 0; rt < 2; ++rt) {
        float inv = 1.0f / st.l[rt];
        int row = base + qrow0 + rt * 16 + l15;
        #pragma unroll
        for (int dt = 0; dt < 4; ++dt) {
            f32x4 ov = st.o[rt][dt] * inv;
            *(f32x4*)&out[(size_t)row * DH + dt * 16 + lg * 4] = ov;
        }
    }
}

// ---------------------------------------------------------------------------
extern "C" void kernel_launch(void* const* d_in, const int* in_sizes, int n_in,
                              void* d_out, int out_size, void* d_ws, size_t ws_size,
                              hipStream_t stream)
{
    const float* x  = (const float*)d_in[0];
    const float* wq = (const float*)d_in[1];
    const float* wk = (const float*)d_in[2];
    const float* wv = (const float*)d_in[3];
    float* out = (float*)d_out;

    // ws layout:
    //   wt  bf16 [3][64][128]       @ 0        (reserve 64 KB)
    //   qw  bf16 [16384][64]        @ 65536    (2 MB)
    //   kw  bf16 [16384][64]        @ +2 MB
    //   vt  bf16 [4][64][4096]      @ +4 MB
    //   po  bf16 [2048][128][64]    @ 6356992  (33.5 MB)
    //   pm/pl f32 [2048][128]       (1 MB each)
    unsigned short* wt = (unsigned short*)d_ws;
    unsigned short* qw = (unsigned short*)((char*)d_ws + 65536);
    unsigned short* kw = qw + (size_t)16384 * DH;
    unsigned short* vt = kw + (size_t)16384 * DH;

    const size_t po_off = 65536u + 3u * 16384u * DH * 2u;
    const size_t po_sz  = (size_t)2048 * 128 * 64 * 2;
    const size_t pm_off = po_off + po_sz;
    const size_t pl_off = pm_off + (size_t)2048 * 128 * 4;
    const size_t need   = pl_off + (size_t)2048 * 128 * 4;

    prep_w_kernel<<<96, 256, 0, stream>>>(wq, wk, wv, wt);
    proj_kernel<<<1024, 64, 0, stream>>>(x, wt, qw, kw, vt);

    if (ws_size >= need) {
        unsigned short* po = (unsigned short*)((char*)d_ws + po_off);
        float* pm = (float*)((char*)d_ws + pm_off);
        float* pl = (float*)((char*)d_ws + pl_off);
        attn_partial_kernel<<<4 * 32 * 16, 256, 0, stream>>>(qw, kw, vt, po, pm, pl);
        attn_combine_kernel<<<4 * 32 * 2, 256, 0, stream>>>(po, pm, pl, out);
    } else {
        attn_direct_kernel<<<4 * 128, 64, 0, stream>>>(qw, kw, vt, out);
    }
}

// Round 7
// 60.531 us; speedup vs baseline: 1.6839x; 1.1548x over previous
//
#include <hip/hip_runtime.h>
#include <hip/hip_bf16.h>

// ---------------------------------------------------------------------------
// Fused causal attention head: B=4, T=4096, E=128, D=64, fp32 in/out.
// prep_w (W -> WT bf16) -> proj (x@W MFMA; q,k row-major bf16, q pre-scaled
// by 0.125*log2(e); V transposed to vt[d][t]) -> attn_partial (compact
// triangular grid, 256-thr block = 128 q-rows x 256-key chunk, 128-key
// staged groups with REGISTER-PREFETCH pipeline, swapped-QK^T in-register
// exp2 softmax, P^T->B-frag via bpermute) -> attn_combine.
// ---------------------------------------------------------------------------

typedef __attribute__((ext_vector_type(4))) float  f32x4;
typedef __attribute__((ext_vector_type(4))) unsigned int u32x4;
typedef __attribute__((ext_vector_type(8))) __bf16 bf16x8;
typedef __attribute__((ext_vector_type(8))) unsigned short u16x8;
typedef __attribute__((ext_vector_type(4))) unsigned short u16x4;

#define T_SEQ 4096
#define DH    64
#define EDIM  128
#define KVB   64
#define KSTR  72    // K_lds row stride (u16), pad -> banks spread
#define VSTR  136   // V_lds row stride (u16), pad -> banks spread
#define QSCALE 0.18033688f   // 0.125 * log2(e): softmax in exp2 domain

__device__ __forceinline__ unsigned short f2bf(float f) {
    unsigned int x = __builtin_bit_cast(unsigned int, f);
    unsigned int r = x + 0x7fffu + ((x >> 16) & 1u);   // RNE
    return (unsigned short)(r >> 16);
}

__device__ __forceinline__ unsigned int cvt_pk_bf16(float lo, float hi) {
    unsigned int d;
    asm("v_cvt_pk_bf16_f32 %0, %1, %2" : "=v"(d) : "v"(lo), "v"(hi));
    return d;
}

__device__ __forceinline__ f32x4 mfma_bf16(u16x8 a, u16x8 b, f32x4 c) {
    return __builtin_amdgcn_mfma_f32_16x16x32_bf16(
        __builtin_bit_cast(bf16x8, a), __builtin_bit_cast(bf16x8, b), c, 0, 0, 0);
}

// --------------------------- prep_w -----------------------------------------
__global__ __launch_bounds__(256) void prep_w_kernel(
    const float* __restrict__ wq, const float* __restrict__ wk,
    const float* __restrict__ wv, unsigned short* __restrict__ wt)
{
    int o = blockIdx.x * 256 + threadIdx.x;
    int m   = o >> 13;
    int rem = o & 8191;
    int d = rem >> 7, e = rem & 127;
    const float* W = (m == 0) ? wq : (m == 1) ? wk : wv;
    wt[o] = f2bf(W[e * DH + d]);
}

// --------------------------- proj: q,k row-major; v transposed --------------
__global__ __launch_bounds__(64) void proj_kernel(
    const float* __restrict__ x, const unsigned short* __restrict__ wt,
    unsigned short* __restrict__ qw, unsigned short* __restrict__ kw,
    unsigned short* __restrict__ vt)
{
    const int l   = threadIdx.x;
    const int l15 = l & 15;
    const int lg  = l >> 4;
    const int row0 = blockIdx.x * 16;      // global row (b*4096 + t)
    const int b    = row0 >> 12;
    const int t0   = row0 & 4095;

    u16x8 af[4];
    #pragma unroll
    for (int kt = 0; kt < 4; ++kt) {
        const float* xp = x + (row0 + l15) * EDIM + kt * 32 + lg * 8;
        f32x4 a = *(const f32x4*)xp;
        f32x4 bb = *(const f32x4*)(xp + 4);
        af[kt] = u16x8{ f2bf(a[0]), f2bf(a[1]), f2bf(a[2]), f2bf(a[3]),
                        f2bf(bb[0]), f2bf(bb[1]), f2bf(bb[2]), f2bf(bb[3]) };
    }

    unsigned short* outs[2] = { qw, kw };
    #pragma unroll
    for (int m = 0; m < 2; ++m) {
        #pragma unroll
        for (int nt = 0; nt < 4; ++nt) {
            f32x4 acc = {};
            #pragma unroll
            for (int kt = 0; kt < 4; ++kt) {
                u16x8 bfrag = *(const u16x8*)(wt + (m * 64 + nt * 16 + l15) * EDIM
                                                 + kt * 32 + lg * 8);
                acc = mfma_bf16(af[kt], bfrag, acc);
            }
            const float sc = (m == 0) ? QSCALE : 1.0f;
            #pragma unroll
            for (int r = 0; r < 4; ++r)
                outs[m][(row0 + lg * 4 + r) * DH + nt * 16 + l15] = f2bf(acc[r] * sc);
        }
    }

    // v: store transposed vt[b][d][t]
    #pragma unroll
    for (int nt = 0; nt < 4; ++nt) {
        f32x4 acc = {};
        #pragma unroll
        for (int kt = 0; kt < 4; ++kt) {
            u16x8 bfrag = *(const u16x8*)(wt + (2 * 64 + nt * 16 + l15) * EDIM
                                             + kt * 32 + lg * 8);
            acc = mfma_bf16(af[kt], bfrag, acc);
        }
        u16x4 pv = { f2bf(acc[0]), f2bf(acc[1]), f2bf(acc[2]), f2bf(acc[3]) };
        *(u16x4*)(vt + ((size_t)(b * DH + nt * 16 + l15)) * T_SEQ + t0 + lg * 4) = pv;
    }
}

// --------------------------- staging helpers (128-key group) ----------------
__device__ __forceinline__ void loadK(u16x8 kr[4], const unsigned short* kgB,
                                      int kv0, int tid) {
    #pragma unroll
    for (int j = 0; j < 4; ++j) {
        int gi = tid + j * 256;                  // 0..1023: K 128 rows x 8 gran
        kr[j] = *(const u16x8*)(kgB + (size_t)(kv0 + (gi >> 3)) * DH + (gi & 7) * 8);
    }
}
__device__ __forceinline__ void loadV(u16x8 vr[4], const unsigned short* vtB,
                                      int kv0, int tid) {
    #pragma unroll
    for (int j = 0; j < 4; ++j) {
        int gi = tid + j * 256;                  // 0..1023: V 64 rows x 16 gran
        vr[j] = *(const u16x8*)(vtB + (size_t)(gi >> 4) * T_SEQ + kv0 + (gi & 15) * 8);
    }
}
__device__ __forceinline__ void writeK(const u16x8 kr[4], unsigned short* K_lds,
                                       int tid) {
    #pragma unroll
    for (int j = 0; j < 4; ++j) {
        int gi = tid + j * 256;
        *(u16x8*)&K_lds[(gi >> 3) * KSTR + (gi & 7) * 8] = kr[j];
    }
}
__device__ __forceinline__ void writeV(const u16x8 vr[4], unsigned short* V_lds,
                                       int tid) {
    #pragma unroll
    for (int j = 0; j < 4; ++j) {
        int gi = tid + j * 256;
        *(u16x8*)&V_lds[(gi >> 4) * VSTR + (gi & 15) * 8] = vr[j];
    }
}

// --------------------------- phase 1: pipelined split-KV flash --------------
__global__ __launch_bounds__(256, 3) void attn_partial_kernel(
    const unsigned short* __restrict__ qg, const unsigned short* __restrict__ kg,
    const unsigned short* __restrict__ vt,
    unsigned short* __restrict__ po, float* __restrict__ pm, float* __restrict__ pl)
{
    // compact triangular grid: bid -> (b, q128, ch), only active blocks
    const int bid = blockIdx.x;
    const int b   = bid / 272;
    const int i   = bid - b * 272;
    int k = (int)((__builtin_sqrtf((float)(4 * i + 1)) - 1.0f) * 0.5f);
    while (k * (k + 1) > i) --k;
    while ((k + 1) * (k + 2) <= i) ++k;
    const int r    = i - k * (k + 1);
    const int hiq  = (r >= k + 1);
    const int q128 = 2 * k + hiq;
    const int ch   = hiq ? r - (k + 1) : r;

    __shared__ unsigned short K_lds[128 * KSTR];   // 128 keys x 64 d
    __shared__ unsigned short V_lds[64 * VSTR];    // 64 d x 128 keys

    const int tid = threadIdx.x;
    const int w   = tid >> 6;
    const int l   = tid & 63;
    const int l15 = l & 15;
    const int lg  = l >> 4;

    const int base   = b * T_SEQ;
    const int qrow0w = q128 * 128 + w * 32;
    const int kvb = ch * 256;
    const int kve = min(kvb + 256, q128 * 128 + 128);
    const bool ng2 = (kve - kvb) > 128;

    const unsigned short* kgB = kg + (size_t)base * DH;
    const unsigned short* vtB = vt + (size_t)b * DH * T_SEQ;

    // Q fragments
    u16x8 qf[2][2];
    #pragma unroll
    for (int rt = 0; rt < 2; ++rt) {
        const unsigned short* qrow = qg + (base + qrow0w + rt * 16 + l15) * DH;
        qf[rt][0] = *(const u16x8*)(qrow + 0 + lg * 8);
        qf[rt][1] = *(const u16x8*)(qrow + 32 + lg * 8);
    }

    f32x4 o_acc[2][4];
    float m_run[2], l_run[2];
    #pragma unroll
    for (int rt = 0; rt < 2; ++rt) {
        #pragma unroll
        for (int dt = 0; dt < 4; ++dt) o_acc[rt][dt] = f32x4{};
        m_run[rt] = -1e30f; l_run[rt] = 0.0f;
    }

    const int src0 = l15 + 32 * (lg & 1);
    const int src1 = src0 + 16;
    const bool hi  = (lg >> 1) != 0;

    // one 64-key tile from LDS (tt = position in group)
    auto compute_tile = [&](int kv0, int tt) {
        if (kv0 > qrow0w + 31) return;           // wave-uniform causal skip
        const unsigned short* Kt = K_lds + (tt * 64) * KSTR;
        const unsigned short* Vt = V_lds + tt * 64;

        u16x8 kf[4][2];
        #pragma unroll
        for (int nt = 0; nt < 4; ++nt)
            #pragma unroll
            for (int kt = 0; kt < 2; ++kt)
                kf[nt][kt] = *(const u16x8*)&Kt[(nt * 16 + l15) * KSTR
                                                + kt * 32 + lg * 8];

        f32x4 s[2][4];
        __builtin_amdgcn_s_setprio(1);
        #pragma unroll
        for (int rt = 0; rt < 2; ++rt)
            #pragma unroll
            for (int nt = 0; nt < 4; ++nt) {
                f32x4 a = {};
                a = mfma_bf16(kf[nt][0], qf[rt][0], a);
                a = mfma_bf16(kf[nt][1], qf[rt][1], a);
                s[rt][nt] = a;
            }
        __builtin_amdgcn_s_setprio(0);

        if (kv0 + KVB - 1 > qrow0w) {            // diagonal-straddling mask
            #pragma unroll
            for (int rt = 0; rt < 2; ++rt)
                #pragma unroll
                for (int nt = 0; nt < 4; ++nt)
                    #pragma unroll
                    for (int rr = 0; rr < 4; ++rr) {
                        int kj = kv0 + nt * 16 + lg * 4 + rr;
                        int qi = qrow0w + rt * 16 + l15;
                        if (kj > qi) s[rt][nt][rr] = -1e30f;
                    }
        }

        // in-register online softmax (exp2 domain; 2 shfls per reduce)
        float sc2[2];
        bool grow = false;
        unsigned int pk[2][4][2];
        #pragma unroll
        for (int rt = 0; rt < 2; ++rt) {
            float mx = s[rt][0][0];
            #pragma unroll
            for (int nt = 0; nt < 4; ++nt)
                #pragma unroll
                for (int rr = 0; rr < 4; ++rr)
                    mx = fmaxf(mx, s[rt][nt][rr]);
            mx = fmaxf(mx, __shfl_xor(mx, 16));
            mx = fmaxf(mx, __shfl_xor(mx, 32));

            float mold = m_run[rt];
            float mnew = fmaxf(mold, mx);
            grow |= (mx > mold);
            float sc = exp2f(mold - mnew);
            sc2[rt] = sc;
            m_run[rt] = mnew;

            float rs = 0.0f;
            #pragma unroll
            for (int nt = 0; nt < 4; ++nt)
                #pragma unroll
                for (int rr = 0; rr < 4; ++rr) {
                    float p = exp2f(s[rt][nt][rr] - mnew);
                    s[rt][nt][rr] = p;
                    rs += p;
                }
            rs += __shfl_xor(rs, 16);
            rs += __shfl_xor(rs, 32);
            l_run[rt] = l_run[rt] * sc + rs;

            #pragma unroll
            for (int nt = 0; nt < 4; ++nt) {
                pk[rt][nt][0] = cvt_pk_bf16(s[rt][nt][0], s[rt][nt][1]);
                pk[rt][nt][1] = cvt_pk_bf16(s[rt][nt][2], s[rt][nt][3]);
            }
        }
        if (__any(grow)) {
            #pragma unroll
            for (int rt = 0; rt < 2; ++rt)
                #pragma unroll
                for (int dt = 0; dt < 4; ++dt)
                    o_acc[rt][dt] *= sc2[rt];
        }

        // O^T += V^T P^T (P B-frag via bpermute exchange)
        __builtin_amdgcn_s_setprio(1);
        #pragma unroll
        for (int kt = 0; kt < 2; ++kt) {
            u16x8 vf[4];
            #pragma unroll
            for (int dt = 0; dt < 4; ++dt)
                vf[dt] = *(const u16x8*)&Vt[(dt * 16 + l15) * VSTR
                                            + kt * 32 + lg * 8];
            #pragma unroll
            for (int rt = 0; rt < 2; ++rt) {
                unsigned int pb[4];
                #pragma unroll
                for (int t = 0; t < 4; ++t) {
                    int src = (t < 2) ? src0 : src1;
                    unsigned int pa  = __shfl(pk[rt][2 * kt][t & 1], src);
                    unsigned int pbv = __shfl(pk[rt][2 * kt + 1][t & 1], src);
                    pb[t] = hi ? pbv : pa;
                }
                u32x4 pbq = { pb[0], pb[1], pb[2], pb[3] };
                u16x8 pbf = __builtin_bit_cast(u16x8, pbq);
                #pragma unroll
                for (int dt = 0; dt < 4; ++dt)
                    o_acc[rt][dt] = mfma_bf16(vf[dt], pbf, o_acc[rt][dt]);
            }
        }
        __builtin_amdgcn_s_setprio(0);
    };

    // ---- pipelined main: group 0 staged, group 1 prefetched during compute
    u16x8 kr[4], vr[4];
    loadK(kr, kgB, kvb, tid);
    loadV(vr, vtB, kvb, tid);
    writeK(kr, K_lds, tid);
    writeV(vr, V_lds, tid);
    __syncthreads();

    if (ng2) loadK(kr, kgB, kvb + 128, tid);     // prefetch next K
    compute_tile(kvb, 0);
    if (ng2) loadV(vr, vtB, kvb + 128, tid);     // prefetch next V
    compute_tile(kvb + 64, 1);
    __syncthreads();

    if (ng2) {
        writeK(kr, K_lds, tid);
        writeV(vr, V_lds, tid);
        __syncthreads();
        compute_tile(kvb + 128, 0);
        compute_tile(kvb + 192, 1);
    }

    // ---- write partials (bf16 O, f32 m/l) ----
    const int pidx = (b * 32 + q128) * 16 + ch;
    unsigned short* pob = po + (size_t)pidx * 8192;   // [128][64] bf16
    #pragma unroll
    for (int rt = 0; rt < 2; ++rt) {
        int row = w * 32 + rt * 16 + l15;
        #pragma unroll
        for (int dt = 0; dt < 4; ++dt) {
            unsigned int w0 = cvt_pk_bf16(o_acc[rt][dt][0], o_acc[rt][dt][1]);
            unsigned int w1 = cvt_pk_bf16(o_acc[rt][dt][2], o_acc[rt][dt][3]);
            *(unsigned int*)&pob[row * 64 + dt * 16 + lg * 4]     = w0;
            *(unsigned int*)&pob[row * 64 + dt * 16 + lg * 4 + 2] = w1;
        }
        if (lg == 0) {
            pm[pidx * 128 + row] = m_run[rt];
            pl[pidx * 128 + row] = l_run[rt];
        }
    }
}

// --------------------------- phase 2: combine -------------------------------
__global__ __launch_bounds__(256) void attn_combine_kernel(
    const unsigned short* __restrict__ po, const float* __restrict__ pm,
    const float* __restrict__ pl, float* __restrict__ out)
{
    const int blk  = blockIdx.x;          // (b*32+q128)*2 + half
    const int half = blk & 1;
    const int tb   = blk >> 1;            // b*32 + q128
    const int q128 = tb & 31;
    const int b    = tb >> 5;
    const int nch  = (q128 >> 1) + 1;
    const int row  = half * 64 + (threadIdx.x >> 2);   // 0..127
    const int d0   = (threadIdx.x & 3) * 16;
    const int bp   = tb * 16;

    float mstar = -1e30f;
    for (int i = 0; i < nch; ++i)
        mstar = fmaxf(mstar, pm[(bp + i) * 128 + row]);

    float lsum = 0.0f;
    float a[16] = {};
    for (int i = 0; i < nch; ++i) {
        float wi = exp2f(pm[(bp + i) * 128 + row] - mstar);
        lsum += wi * pl[(bp + i) * 128 + row];
        const unsigned short* p = po + (size_t)(bp + i) * 8192 + row * 64 + d0;
        u16x8 v0 = *(const u16x8*)p;
        u16x8 v1 = *(const u16x8*)(p + 8);
        #pragma unroll
        for (int j = 0; j < 8; ++j) {
            unsigned int u0 = (unsigned int)v0[j] << 16;
            unsigned int u1 = (unsigned int)v1[j] << 16;
            a[j]     += wi * __builtin_bit_cast(float, u0);
            a[8 + j] += wi * __builtin_bit_cast(float, u1);
        }
    }
    const float inv = 1.0f / lsum;
    float* op = out + (size_t)(b * T_SEQ + q128 * 128 + row) * DH + d0;
    #pragma unroll
    for (int j = 0; j < 4; ++j) {
        f32x4 o0 = { a[4*(j&1)+0 + 8*(j>>1)] * inv, a[4*(j&1)+1 + 8*(j>>1)] * inv,
                     a[4*(j&1)+2 + 8*(j>>1)] * inv, a[4*(j&1)+3 + 8*(j>>1)] * inv };
        *(f32x4*)(op + j * 4) = o0;
    }
}

// --------------------------- fallback: direct (global K/V reads) ------------
__global__ __launch_bounds__(64, 4) void attn_direct_kernel(
    const unsigned short* __restrict__ qg, const unsigned short* __restrict__ kg,
    const unsigned short* __restrict__ vt, float* __restrict__ out)
{
    const int bid = blockIdx.x;           // b*128 + q32
    const int q32 = bid & 127;
    const int b   = bid >> 7;
    const int l = threadIdx.x, l15 = l & 15, lg = l >> 4;
    const int qrow0 = q32 * 32;
    const int base  = b * T_SEQ;
    const unsigned short* kp = kg + (size_t)base * DH;
    const unsigned short* vp = vt + (size_t)b * DH * T_SEQ;

    u16x8 qf[2][2];
    #pragma unroll
    for (int rt = 0; rt < 2; ++rt) {
        const unsigned short* qrow = qg + (base + qrow0 + rt * 16 + l15) * DH;
        qf[rt][0] = *(const u16x8*)(qrow + 0 + lg * 8);
        qf[rt][1] = *(const u16x8*)(qrow + 32 + lg * 8);
    }

    f32x4 o_acc[2][4];
    float m_run[2], l_run[2];
    #pragma unroll
    for (int rt = 0; rt < 2; ++rt) {
        #pragma unroll
        for (int dt = 0; dt < 4; ++dt) o_acc[rt][dt] = f32x4{};
        m_run[rt] = -1e30f; l_run[rt] = 0.0f;
    }

    const int src0 = l15 + 32 * (lg & 1);
    const int src1 = src0 + 16;
    const bool hi  = (lg >> 1) != 0;

    for (int kv0 = 0; kv0 <= qrow0 + 31; kv0 += KVB) {
        u16x8 kf[4][2];
        #pragma unroll
        for (int nt = 0; nt < 4; ++nt)
            #pragma unroll
            for (int kt = 0; kt < 2; ++kt)
                kf[nt][kt] = *(const u16x8*)(kp + (kv0 + nt * 16 + l15) * DH
                                                + kt * 32 + lg * 8);
        f32x4 s[2][4];
        #pragma unroll
        for (int rt = 0; rt < 2; ++rt)
            #pragma unroll
            for (int nt = 0; nt < 4; ++nt) {
                f32x4 a = {};
                a = mfma_bf16(kf[nt][0], qf[rt][0], a);
                a = mfma_bf16(kf[nt][1], qf[rt][1], a);
                s[rt][nt] = a;
            }
        if (kv0 + KVB - 1 > qrow0) {
            #pragma unroll
            for (int rt = 0; rt < 2; ++rt)
                #pragma unroll
                for (int nt = 0; nt < 4; ++nt)
                    #pragma unroll
                    for (int rr = 0; rr < 4; ++rr) {
                        int kj = kv0 + nt * 16 + lg * 4 + rr;
                        int qi = qrow0 + rt * 16 + l15;
                        if (kj > qi) s[rt][nt][rr] = -1e30f;
                    }
        }
        float sc2[2];
        bool grow = false;
        unsigned int pk[2][4][2];
        #pragma unroll
        for (int rt = 0; rt < 2; ++rt) {
            float mx = s[rt][0][0];
            #pragma unroll
            for (int nt = 0; nt < 4; ++nt)
                #pragma unroll
                for (int rr = 0; rr < 4; ++rr)
                    mx = fmaxf(mx, s[rt][nt][rr]);
            mx = fmaxf(mx, __shfl_xor(mx, 16));
            mx = fmaxf(mx, __shfl_xor(mx, 32));
            float mold = m_run[rt];
            float mnew = fmaxf(mold, mx);
            grow |= (mx > mold);
            float sc = exp2f(mold - mnew);
            sc2[rt] = sc;
            m_run[rt] = mnew;
            float rs = 0.0f;
            #pragma unroll
            for (int nt = 0; nt < 4; ++nt)
                #pragma unroll
                for (int rr = 0; rr < 4; ++rr) {
                    float p = exp2f(s[rt][nt][rr] - mnew);
                    s[rt][nt][rr] = p;
                    rs += p;
                }
            rs += __shfl_xor(rs, 16);
            rs += __shfl_xor(rs, 32);
            l_run[rt] = l_run[rt] * sc + rs;
            #pragma unroll
            for (int nt = 0; nt < 4; ++nt) {
                pk[rt][nt][0] = cvt_pk_bf16(s[rt][nt][0], s[rt][nt][1]);
                pk[rt][nt][1] = cvt_pk_bf16(s[rt][nt][2], s[rt][nt][3]);
            }
        }
        if (__any(grow)) {
            #pragma unroll
            for (int rt = 0; rt < 2; ++rt)
                #pragma unroll
                for (int dt = 0; dt < 4; ++dt)
                    o_acc[rt][dt] *= sc2[rt];
        }
        #pragma unroll
        for (int kt = 0; kt < 2; ++kt) {
            u16x8 vf[4];
            #pragma unroll
            for (int dt = 0; dt < 4; ++dt)
                vf[dt] = *(const u16x8*)(vp + (size_t)(dt * 16 + l15) * T_SEQ
                                            + kv0 + kt * 32 + lg * 8);
            #pragma unroll
            for (int rt = 0; rt < 2; ++rt) {
                unsigned int pb[4];
                #pragma unroll
                for (int t = 0; t < 4; ++t) {
                    int src = (t < 2) ? src0 : src1;
                    unsigned int pa  = __shfl(pk[rt][2 * kt][t & 1], src);
                    unsigned int pbv = __shfl(pk[rt][2 * kt + 1][t & 1], src);
                    pb[t] = hi ? pbv : pa;
                }
                u32x4 pbq = { pb[0], pb[1], pb[2], pb[3] };
                u16x8 pbf = __builtin_bit_cast(u16x8, pbq);
                #pragma unroll
                for (int dt = 0; dt < 4; ++dt)
                    o_acc[rt][dt] = mfma_bf16(vf[dt], pbf, o_acc[rt][dt]);
            }
        }
    }

    #pragma unroll
    for (int rt = 0; rt < 2; ++rt) {
        float inv = 1.0f / l_run[rt];
        int row = base + qrow0 + rt * 16 + l15;
        #pragma unroll
        for (int dt = 0; dt < 4; ++dt) {
            f32x4 ov = o_acc[rt][dt] * inv;
            *(f32x4*)&out[(size_t)row * DH + dt * 16 + lg * 4] = ov;
        }
    }
}

// ---------------------------------------------------------------------------
extern "C" void kernel_launch(void* const* d_in, const int* in_sizes, int n_in,
                              void* d_out, int out_size, void* d_ws, size_t ws_size,
                              hipStream_t stream)
{
    const float* x  = (const float*)d_in[0];
    const float* wq = (const float*)d_in[1];
    const float* wk = (const float*)d_in[2];
    const float* wv = (const float*)d_in[3];
    float* out = (float*)d_out;

    // ws layout:
    //   wt  bf16 [3][64][128]       @ 0        (reserve 64 KB)
    //   qw  bf16 [16384][64]        @ 65536    (2 MB)
    //   kw  bf16 [16384][64]        @ +2 MB
    //   vt  bf16 [4][64][4096]      @ +4 MB
    //   po  bf16 [2048][128][64]    @ 6356992  (33.5 MB, sparse use)
    //   pm/pl f32 [2048][128]       (1 MB each)
    unsigned short* wt = (unsigned short*)d_ws;
    unsigned short* qw = (unsigned short*)((char*)d_ws + 65536);
    unsigned short* kw = qw + (size_t)16384 * DH;
    unsigned short* vt = kw + (size_t)16384 * DH;

    const size_t po_off = 65536u + 3u * 16384u * DH * 2u;
    const size_t po_sz  = (size_t)2048 * 128 * 64 * 2;
    const size_t pm_off = po_off + po_sz;
    const size_t pl_off = pm_off + (size_t)2048 * 128 * 4;
    const size_t need   = pl_off + (size_t)2048 * 128 * 4;

    prep_w_kernel<<<96, 256, 0, stream>>>(wq, wk, wv, wt);
    proj_kernel<<<1024, 64, 0, stream>>>(x, wt, qw, kw, vt);

    if (ws_size >= need) {
        unsigned short* po = (unsigned short*)((char*)d_ws + po_off);
        float* pm = (float*)((char*)d_ws + pm_off);
        float* pl = (float*)((char*)d_ws + pl_off);
        attn_partial_kernel<<<4 * 272, 256, 0, stream>>>(qw, kw, vt, po, pm, pl);
        attn_combine_kernel<<<4 * 32 * 2, 256, 0, stream>>>(po, pm, pl, out);
    } else {
        attn_direct_kernel<<<4 * 128, 64, 0, stream>>>(qw, kw, vt, out);
    }
}